// Round 4
// baseline (124.594 us; speedup 1.0000x reference)
//
#include <hip/hip_runtime.h>

#define BB 4
#define CC 3
#define HH 512
#define WW 512
#define NS 81              // 9 x 9 shifts
#define IMG (HH * WW)
#define CHW (CC * IMG)
#define STRIP 4            // rows per k_sims block (1 row per wave)
#define NSTRIP (HH / STRIP)              // 128
#define NSXG 3             // sx groups of 3
#define NBLK (BB * CC * NSTRIP * NSXG)   // 4608  = 3.0 co-residency rounds
#define NP (CC * NSTRIP)                 // 384 partials per (b, slot)

// ws layout: float partials[NBLK][27] at byte 0 (~498 KB); int best[BB*2] after.
#define BEST_OFF (NBLK * 27 * sizeof(float))

// sim(b,sx,sy) = sum over c,i,j (both (i,j) and (i+sx,j+sy) in bounds) of
//               x[b,c,i,j] * x_ref[b,c,i+sx,j+sy]
// One block = (bc, 4-row strip, 3 consecutive sx). One row per wave.
// 27 fp32 accumulators/lane; 16-float ref window -> 72 FMAs per ~4 loads.
__global__ __launch_bounds__(256, 6) void k_sims(const float* __restrict__ xref,
                                                 const float* __restrict__ x,
                                                 float* __restrict__ partials) {
    int bid  = blockIdx.x;
    int sxg  = bid % NSXG;
    int tmp  = bid / NSXG;
    int strip = tmp % NSTRIP;
    int bc   = tmp / NSTRIP;
    const float* xp = x    + (size_t)bc * IMG;
    const float* rp = xref + (size_t)bc * IMG;
    int tid  = threadIdx.x;
    int lane = tid & 63;
    int wave = tid >> 6;
    int j0   = lane << 3;            // 8 floats per lane

    float acc[27];
#pragma unroll
    for (int s = 0; s < 27; ++s) acc[s] = 0.f;

    int ip = strip * STRIP + wave;       // this wave's x row
    const float* xrow = xp + ip * WW + j0;
    float x8[8];
    *(float4*)(x8)     = *(const float4*)(xrow);
    *(float4*)(x8 + 4) = *(const float4*)(xrow + 4);

#pragma unroll
    for (int sxl = 0; sxl < 3; ++sxl) {
        int ii = ip + sxg * 3 + sxl - 4;   // ref row (wave-uniform test)
        if ((unsigned)ii >= HH) continue;
        const float* rrow = rp + ii * WW + j0;
        float w[16];                       // ref cols [j0-4, j0+12)
        if (j0 >= 4) *(float4*)(w) = *(const float4*)(rrow - 4);
        else { w[0] = w[1] = w[2] = w[3] = 0.f; }
        *(float4*)(w + 4) = *(const float4*)(rrow);
        *(float4*)(w + 8) = *(const float4*)(rrow + 4);
        if (j0 + 12 <= WW) *(float4*)(w + 12) = *(const float4*)(rrow + 8);
        else { w[12] = w[13] = w[14] = w[15] = 0.f; }
#pragma unroll
        for (int syi = 0; syi < 9; ++syi)
#pragma unroll
            for (int k = 0; k < 8; ++k)
                acc[sxl * 9 + syi] += x8[k] * w[k + syi];
    }

    // wave reduce (fp32), block combine in LDS, direct store (no atomics)
    __shared__ float part[4][27];
#pragma unroll
    for (int s = 0; s < 27; ++s) {
        float v = acc[s];
        for (int off = 32; off; off >>= 1) v += __shfl_down(v, off, 64);
        if (lane == 0) part[wave][s] = v;
    }
    __syncthreads();
    if (tid < 27)
        partials[bid * 27 + tid] = part[0][tid] + part[1][tid]
                                 + part[2][tid] + part[3][tid];
}

// One block (512 threads) per batch: parallel fp64 reduce of the 384 partials
// per shift-slot (6 threads/slot, 64 independent loads each), then argmax with
// first-index tie-break (strict > keeps lowest index).
__global__ __launch_bounds__(512) void k_argmax(const float* __restrict__ partials,
                                                int* __restrict__ best,
                                                float* __restrict__ outTail) {
    int b = blockIdx.x;
    int t = threadIdx.x;
    __shared__ double lds[486];
    __shared__ double vals[NS];
    if (t < 486) {
        int slot = t / 6;                 // 0..80
        int sub  = t % 6;
        int sxi = slot / 9, syi = slot % 9;
        int sxg = sxi / 3;
        int within = (sxi - sxg * 3) * 9 + syi;
        double acc = 0.0;
#pragma unroll 4
        for (int k = 0; k < NP / 6; ++k) {        // 64 values each
            int q  = sub + 6 * k;                 // q in [0, 384)
            int c  = q >> 7;                      // q / 128
            int st = q & 127;                     // q % 128
            int pb = ((b * CC + c) * NSTRIP + st) * NSXG + sxg;
            acc += (double)partials[pb * 27 + within];
        }
        lds[t] = acc;
    }
    __syncthreads();
    if (t < NS) {
        double s = 0.0;
#pragma unroll
        for (int k = 0; k < 6; ++k) s += lds[t * 6 + k];
        vals[t] = s;
    }
    __syncthreads();
    if (t == 0) {
        double bv = vals[0];
        int bi = 0;
        for (int s = 1; s < NS; ++s)
            if (vals[s] > bv) { bv = vals[s]; bi = s; }
        int sx = bi / 9 - 4;
        int sy = bi % 9 - 4;
        best[b * 2]     = sx;
        best[b * 2 + 1] = sy;
        outTail[b * 2]     = (float)sx;
        outTail[b * 2 + 1] = (float)sy;
    }
}

// out[b,c,i,j] = in-bounds(i-sx, j-sy) ? x[b,c,i-sx,j-sy] : 0
// One block = 2 rows of one (b,c) image; fast path = offset float4 load.
__global__ __launch_bounds__(256) void k_apply(const float* __restrict__ x,
                                               const int* __restrict__ best,
                                               float* __restrict__ out) {
    int blk = blockIdx.x;
    int bc  = blk >> 8;                 // 256 blocks per image (512 rows / 2)
    int tid = threadIdx.x;
    int row = ((blk & 255) << 1) + (tid >> 7);
    int j0  = (tid & 127) << 2;
    int b   = bc / CC;                  // block-uniform -> scalar loads of best
    int sx  = best[b * 2];
    int sy  = best[b * 2 + 1];
    int is  = row - sx;
    float4 v = make_float4(0.f, 0.f, 0.f, 0.f);
    if ((unsigned)is < HH) {
        const float* src = x + (size_t)bc * IMG + is * WW;
        int js0 = j0 - sy;
        if (js0 >= 0 && js0 + 3 < WW) {
            v = *(const float4*)(src + js0);   // 4B-aligned dwordx4, exact (R2/R3)
        } else {
            float* vv = (float*)&v;
#pragma unroll
            for (int k = 0; k < 4; ++k) {
                int js = js0 + k;
                if ((unsigned)js < WW) vv[k] = src[js];
            }
        }
    }
    *(float4*)(out + (size_t)bc * IMG + row * WW + j0) = v;
}

extern "C" void kernel_launch(void* const* d_in, const int* in_sizes, int n_in,
                              void* d_out, int out_size, void* d_ws, size_t ws_size,
                              hipStream_t stream) {
    const float* xref = (const float*)d_in[0];
    const float* x    = (const float*)d_in[1];
    float* out = (float*)d_out;

    float* partials = (float*)d_ws;
    int*   best     = (int*)((char*)d_ws + BEST_OFF);

    k_sims<<<NBLK, 256, 0, stream>>>(xref, x, partials);

    k_argmax<<<BB, 512, 0, stream>>>(partials, best, out + (size_t)BB * CHW);

    int applyBlocks = (BB * CC * HH) / 2;   // 3072
    k_apply<<<applyBlocks, 256, 0, stream>>>(x, best, out);
}

// Round 5
// 110.165 us; speedup vs baseline: 1.1310x; 1.1310x over previous
//
#include <hip/hip_runtime.h>

#define BB 4
#define CC 3
#define HH 512
#define WW 512
#define NS 81              // 9 x 9 shifts
#define IMG (HH * WW)
#define CHW (CC * IMG)
#define STRIP 32           // rows per k_sims block (8 rows per wave)
#define NSTRIP (HH / STRIP)              // 16
#define NBLK (BB * CC * NSTRIP * 9)      // 1728 blocks (one sx each)

// ws layout: float partials[NBLK][9] at byte 0 (~62 KB); int best[BB*2] after.
#define BEST_OFF (NBLK * 9 * sizeof(float))

// sim(b,sx,sy) = sum over c,i,j (both (i,j) and (i+sx,j+sy) in bounds) of
//               x[b,c,i,j] * x_ref[b,c,i+sx,j+sy]
// One block = (bc, 32-row strip, ONE sx). 9 fp32 accumulators/lane; each wave
// owns 8 rows -> 576 FMAs per 54-op shuffle epilogue (was 216:162 in R4).
__global__ __launch_bounds__(256, 8) void k_sims(const float* __restrict__ xref,
                                                 const float* __restrict__ x,
                                                 float* __restrict__ partials) {
    int bid  = blockIdx.x;
    int sxi  = bid % 9;                  // sx = sxi - 4
    int tmp  = bid / 9;
    int strip = tmp % NSTRIP;
    int bc   = tmp / NSTRIP;
    const float* xp = x    + (size_t)bc * IMG;
    const float* rp = xref + (size_t)bc * IMG;
    int tid  = threadIdx.x;
    int lane = tid & 63;
    int wave = tid >> 6;
    int j0   = lane << 3;                // 8 floats per lane
    int sx   = sxi - 4;

    float acc[9];
#pragma unroll
    for (int s = 0; s < 9; ++s) acc[s] = 0.f;

#pragma unroll
    for (int rr = 0; rr < 8; ++rr) {
        int ip = strip * STRIP + wave * 8 + rr;   // this lane's x row
        int ii = ip + sx;                          // ref row (wave-uniform test)
        if ((unsigned)ii >= HH) continue;

        const float* xrow = xp + ip * WW + j0;
        float x8[8];
        *(float4*)(x8)     = *(const float4*)(xrow);
        *(float4*)(x8 + 4) = *(const float4*)(xrow + 4);

        const float* rrow = rp + ii * WW + j0;
        float w[16];                     // ref cols [j0-4, j0+12); zeros = mask
        if (j0 >= 4) *(float4*)(w) = *(const float4*)(rrow - 4);
        else { w[0] = w[1] = w[2] = w[3] = 0.f; }
        *(float4*)(w + 4) = *(const float4*)(rrow);
        *(float4*)(w + 8) = *(const float4*)(rrow + 4);
        if (j0 + 12 <= WW) *(float4*)(w + 12) = *(const float4*)(rrow + 8);
        else { w[12] = w[13] = w[14] = w[15] = 0.f; }

#pragma unroll
        for (int syi = 0; syi < 9; ++syi)
#pragma unroll
            for (int k = 0; k < 8; ++k)
                acc[syi] += x8[k] * w[k + syi];
    }

    // wave reduce (fp32), block combine in LDS, direct store (no atomics)
    __shared__ float part[4][9];
#pragma unroll
    for (int s = 0; s < 9; ++s) {
        float v = acc[s];
        for (int off = 32; off; off >>= 1) v += __shfl_down(v, off, 64);
        if (lane == 0) part[wave][s] = v;
    }
    __syncthreads();
    if (tid < 9)
        partials[bid * 9 + tid] = part[0][tid] + part[1][tid]
                                + part[2][tid] + part[3][tid];
}

// One block (512 threads) per batch: parallel fp64 reduce of the 48 partials
// per shift-slot (6 threads/slot, 8 independent loads each), then argmax with
// first-index tie-break (strict > keeps lowest index).
__global__ __launch_bounds__(512) void k_argmax(const float* __restrict__ partials,
                                                int* __restrict__ best,
                                                float* __restrict__ outTail) {
    int b = blockIdx.x;
    int t = threadIdx.x;
    __shared__ double lds[486];
    __shared__ double vals[NS];
    if (t < 486) {
        int slot = t / 6;                 // 0..80
        int sub  = t % 6;
        int sxi = slot / 9, syi = slot % 9;
        double acc = 0.0;
#pragma unroll
        for (int k = 0; k < 8; ++k) {     // 8 values each
            int q  = sub * 8 + k;         // q in [0, 48)
            int c  = q >> 4;              // q / 16
            int st = q & 15;              // q % 16
            int pb = ((b * CC + c) * NSTRIP + st) * 9 + sxi;
            acc += (double)partials[pb * 9 + syi];
        }
        lds[t] = acc;
    }
    __syncthreads();
    if (t < NS) {
        double s = 0.0;
#pragma unroll
        for (int k = 0; k < 6; ++k) s += lds[t * 6 + k];
        vals[t] = s;
    }
    __syncthreads();
    if (t == 0) {
        double bv = vals[0];
        int bi = 0;
        for (int s = 1; s < NS; ++s)
            if (vals[s] > bv) { bv = vals[s]; bi = s; }
        int sx = bi / 9 - 4;
        int sy = bi % 9 - 4;
        best[b * 2]     = sx;
        best[b * 2 + 1] = sy;
        outTail[b * 2]     = (float)sx;
        outTail[b * 2 + 1] = (float)sy;
    }
}

// out[b,c,i,j] = in-bounds(i-sx, j-sy) ? x[b,c,i-sx,j-sy] : 0
// One block = 2 rows of one (b,c) image; fast path = offset float4 load.
__global__ __launch_bounds__(256) void k_apply(const float* __restrict__ x,
                                               const int* __restrict__ best,
                                               float* __restrict__ out) {
    int blk = blockIdx.x;
    int bc  = blk >> 8;                 // 256 blocks per image (512 rows / 2)
    int tid = threadIdx.x;
    int row = ((blk & 255) << 1) + (tid >> 7);
    int j0  = (tid & 127) << 2;
    int b   = bc / CC;                  // block-uniform -> scalar loads of best
    int sx  = best[b * 2];
    int sy  = best[b * 2 + 1];
    int is  = row - sx;
    float4 v = make_float4(0.f, 0.f, 0.f, 0.f);
    if ((unsigned)is < HH) {
        const float* src = x + (size_t)bc * IMG + is * WW;
        int js0 = j0 - sy;
        if (js0 >= 0 && js0 + 3 < WW) {
            v = *(const float4*)(src + js0);   // 4B-aligned dwordx4, exact (R2-R4)
        } else {
            float* vv = (float*)&v;
#pragma unroll
            for (int k = 0; k < 4; ++k) {
                int js = js0 + k;
                if ((unsigned)js < WW) vv[k] = src[js];
            }
        }
    }
    *(float4*)(out + (size_t)bc * IMG + row * WW + j0) = v;
}

extern "C" void kernel_launch(void* const* d_in, const int* in_sizes, int n_in,
                              void* d_out, int out_size, void* d_ws, size_t ws_size,
                              hipStream_t stream) {
    const float* xref = (const float*)d_in[0];
    const float* x    = (const float*)d_in[1];
    float* out = (float*)d_out;

    float* partials = (float*)d_ws;
    int*   best     = (int*)((char*)d_ws + BEST_OFF);

    k_sims<<<NBLK, 256, 0, stream>>>(xref, x, partials);

    k_argmax<<<BB, 512, 0, stream>>>(partials, best, out + (size_t)BB * CHW);

    int applyBlocks = (BB * CC * HH) / 2;   // 3072
    k_apply<<<applyBlocks, 256, 0, stream>>>(x, best, out);
}